// Round 1
// baseline (2330.760 us; speedup 1.0000x reference)
//
#include <hip/hip_runtime.h>
#include <cstdint>
#include <cstddef>

#define N_ 8192
#define K_ 32
#define FTOT 464      // 400 dist + 16 dmap + 15 dir + 15 vec + 9 rot + 9 pad
#define FCHUNK 116    // FTOT / 4 waves

__device__ __forceinline__ float bf16tof(unsigned short u){
  union { unsigned int i; float f; } v; v.i = ((unsigned int)u) << 16; return v.f;
}
__device__ __forceinline__ unsigned short ftobf16(float f){
  union { float f; unsigned int i; } v; v.f = f;
  unsigned int x = v.i;
  x += 0x7fffu + ((x >> 16) & 1u);   // round-to-nearest-even
  return (unsigned short)(x >> 16);
}
__device__ __forceinline__ float fast_gelu(float x){
  // jax.nn.gelu default (approximate=True, tanh form)
  float y = 0.7978845608028654f * (x + 0.044715f * x * x * x);
  float e = __expf(2.0f * y);            // e=inf -> t=1 ; e=0 -> t=-1 (correct limits)
  float t = 1.0f - 2.0f / (e + 1.0f);
  return 0.5f * x * (1.0f + t);
}

struct Frame { float e1x,e1y,e1z, e2x,e2y,e2z, e3x,e3y,e3z, tx,ty,tz; };

__device__ __forceinline__ Frame calc_frame(const float* p){
  Frame fr;
  float tx=p[3], ty=p[4], tz=p[5];
  float v1x=p[6]-tx, v1y=p[7]-ty, v1z=p[8]-tz;
  float v2x=p[0]-tx, v2y=p[1]-ty, v2z=p[2]-tz;
  float n1 = sqrtf(v1x*v1x+v1y*v1y+v1z*v1z) + 1e-6f;
  float e1x=v1x/n1, e1y=v1y/n1, e1z=v1z/n1;
  float dp = v2x*e1x+v2y*e1y+v2z*e1z;
  float ux=v2x-dp*e1x, uy=v2y-dp*e1y, uz=v2z-dp*e1z;
  float n2 = sqrtf(ux*ux+uy*uy+uz*uz) + 1e-6f;
  float e2x=ux/n2, e2y=uy/n2, e2z=uz/n2;
  fr.e1x=e1x; fr.e1y=e1y; fr.e1z=e1z;
  fr.e2x=e2x; fr.e2y=e2y; fr.e2z=e2z;
  fr.e3x = e1y*e2z - e1z*e2y;
  fr.e3y = e1z*e2x - e1x*e2z;
  fr.e3z = e1x*e2y - e1y*e2x;
  fr.tx=tx; fr.ty=ty; fr.tz=tz;
  return fr;
}

// Concatenated feature->weight mapping:
// [0,400) dist RBF, [400,416) dmap RBF, [416,431) dirs, [431,446) rel_vec/10,
// [446,455) rot, [455,464) zero pad.
__device__ __forceinline__ float load_wcat(int f, int p,
    const float* Wdist, const float* Wdmap, const float* Wdir,
    const float* Wvec, const float* Wrot){
  if (f < 400) return Wdist[f*64 + p];
  if (f < 416) return Wdmap[(f-400)*64 + p];
  if (f < 431) return Wdir[(f-416)*64 + p];
  if (f < 446) return Wvec[(f-431)*64 + p];
  if (f < 455) return Wrot[(f-446)*64 + p];
  return 0.0f;
}

__global__ __launch_bounds__(256, 2)
void dsd_kernel(const float* __restrict__ pos, const float* __restrict__ dmap,
    const int* __restrict__ nbr, const int* __restrict__ resi,
    const int* __restrict__ chain, const int* __restrict__ batch,
    const float* __restrict__ mask,
    const float* __restrict__ W_rel, const float* __restrict__ W_dmap,
    const float* __restrict__ W_dist, const float* __restrict__ W_dir,
    const float* __restrict__ W_rot, const float* __restrict__ W_vec,
    const float* __restrict__ ln_g, const float* __restrict__ ln_b,
    const float* __restrict__ W1, const float* __restrict__ b1,
    const float* __restrict__ W2, const float* __restrict__ b2,
    float* __restrict__ out)
{
  __shared__ unsigned short sW1h[64*128];   // bf16 [p][j]
  __shared__ unsigned short sW2h[128*64];   // bf16 [j][p]
  __shared__ float sFeat[2][FTOT];
  __shared__ float sD[2][25];
  __shared__ float sPosJ[2][15];
  __shared__ float sPosI[15];
  __shared__ float sFr[9];                  // e1,e2,e3 of node n
  __shared__ float sT[3];
  __shared__ float sPart[2][4][64];
  __shared__ float sXv[2][64];
  __shared__ float sH[2][128];
  __shared__ float sOutP[2][2][64];         // [half][pair][p]
  __shared__ int   sRel[2], sSame[2];
  __shared__ float sPm[2], sDv[2];

  const int tid  = threadIdx.x;
  const int w    = tid >> 6;
  const int lane = tid & 63;
  const int n    = blockIdx.x;

  const float lng = ln_g[lane];
  const float lnb = ln_b[lane];
  const float b2v = b2[lane];
  const float b1v = b1[tid & 127];

  // Per-wave chunk of the concatenated weight matrix, fp32 in registers.
  float Wreg[FCHUNK];
  #pragma unroll
  for (int i = 0; i < FCHUNK; ++i)
    Wreg[i] = load_wcat(w*FCHUNK + i, lane, W_dist, W_dmap, W_dir, W_vec, W_rot);

  for (int idx = tid; idx < 64*128; idx += 256) sW1h[idx] = ftobf16(W1[idx]);
  for (int idx = tid; idx < 128*64; idx += 256) sW2h[idx] = ftobf16(W2[idx]);

  if (tid < 15) sPosI[tid] = pos[n*15 + tid];
  if (tid < 18){ int pr = tid/9; sFeat[pr][455 + (tid - pr*9)] = 0.0f; }  // zero pad
  if (tid == 0){
    Frame fr = calc_frame(&pos[n*15]);
    sFr[0]=fr.e1x; sFr[1]=fr.e1y; sFr[2]=fr.e1z;
    sFr[3]=fr.e2x; sFr[4]=fr.e2y; sFr[5]=fr.e2z;
    sFr[6]=fr.e3x; sFr[7]=fr.e3y; sFr[8]=fr.e3z;
    sT[0]=fr.tx; sT[1]=fr.ty; sT[2]=fr.tz;
  }
  __syncthreads();

  const int   resi_n  = resi[n];
  const int   chain_n = chain[n];
  const int   batch_n = batch[n];
  const float mask_n  = mask[n];
  const size_t out_mask_base = (size_t)N_ * K_ * 64;

  #pragma unroll 1
  for (int it = 0; it < 16; ++it){
    const int k0 = it*2;
    // ---- S0: load neighbor positions + per-pair scalars ----
    if (tid < 30){
      int pr = tid/15, q = tid - pr*15;
      int nb = nbr[n*K_ + k0 + pr];
      int j  = nb < 0 ? 0 : nb;
      sPosJ[pr][q] = pos[j*15 + q];
    } else if (tid >= 32 && tid < 34){
      int pr = tid - 32;
      int nb = nbr[n*K_ + k0 + pr];
      int valid = (nb != -1) ? 1 : 0;
      int j  = nb < 0 ? 0 : nb;
      int rl = resi[j] - resi_n;
      rl = rl < -32 ? -32 : (rl > 32 ? 32 : rl);
      sRel[pr]  = rl + 32;
      sSame[pr] = (chain[j] == chain_n && batch[j] == batch_n) ? 1 : 0;
      sPm[pr]   = mask_n * mask[j] * (float)valid;
      sDv[pr]   = dmap[(size_t)n * N_ + j];
    }
    __syncthreads();
    // ---- S1: distances, rot, dirs/vec, dmap RBF, mask store ----
    if (tid < 50){
      int pr = tid/25, q = tid - pr*25;
      int a = q/5, b = q - a*5;
      float dx = sPosI[a*3+0] - sPosJ[pr][b*3+0];
      float dy = sPosI[a*3+1] - sPosJ[pr][b*3+1];
      float dz = sPosI[a*3+2] - sPosJ[pr][b*3+2];
      sD[pr][q] = sqrtf(dx*dx + dy*dy + dz*dz);
    } else if (tid >= 64 && tid < 82){
      int mm = tid - 64;
      int pr = mm/9, r9 = mm - pr*9;
      int i = r9/3, l = r9 - i*3;
      Frame fj = calc_frame(sPosJ[pr]);
      float el0 = (l==0) ? fj.e1x : (l==1) ? fj.e2x : fj.e3x;
      float el1 = (l==0) ? fj.e1y : (l==1) ? fj.e2y : fj.e3y;
      float el2 = (l==0) ? fj.e1z : (l==1) ? fj.e2z : fj.e3z;
      sFeat[pr][446 + r9] = sFr[i*3+0]*el0 + sFr[i*3+1]*el1 + sFr[i*3+2]*el2;
    } else if (tid >= 96 && tid < 106){
      int mm = tid - 96;
      int pr = mm/5, a = mm - (mm/5)*5;
      float x0 = sPosJ[pr][a*3+0] - sT[0];
      float x1 = sPosJ[pr][a*3+1] - sT[1];
      float x2 = sPosJ[pr][a*3+2] - sT[2];
      float r0 = sFr[0]*x0 + sFr[1]*x1 + sFr[2]*x2;
      float r1 = sFr[3]*x0 + sFr[4]*x1 + sFr[5]*x2;
      float r2 = sFr[6]*x0 + sFr[7]*x1 + sFr[8]*x2;
      float inv = 1.0f/(sqrtf(r0*r0 + r1*r1 + r2*r2) + 1e-6f);
      sFeat[pr][416 + a*3 + 0] = r0*inv;
      sFeat[pr][416 + a*3 + 1] = r1*inv;
      sFeat[pr][416 + a*3 + 2] = r2*inv;
      sFeat[pr][431 + a*3 + 0] = r0*0.1f;
      sFeat[pr][431 + a*3 + 1] = r1*0.1f;
      sFeat[pr][431 + a*3 + 2] = r2*0.1f;
    } else if (tid >= 120 && tid < 122){
      int pr = tid - 120;
      out[out_mask_base + (size_t)n*K_ + k0 + pr] = sPm[pr];
    } else if (tid >= 128 && tid < 160){
      int mm = tid - 128;
      int pr = mm >> 4, c = mm & 15;
      float z = (sDv[pr] - (float)c*(22.0f/15.0f)) * (1.0f/1.375f);
      sFeat[pr][400 + c] = (sPm[pr] > 0.0f) ? __expf(-z*z) : 0.0f;
    }
    __syncthreads();
    // ---- S2: 2x400 distance RBF features ----
    #pragma unroll
    for (int r = 0; r < 4; ++r){
      int idx = tid + r*256;
      if (idx < 800){
        int pr = idx / 400;
        int f  = idx - pr*400;
        int a   = f / 80;
        int rem = f - a*80;
        int b = rem >> 4, c = rem & 15;
        float d = sD[pr][a*5 + b];
        float z = (d - (float)c*(22.0f/15.0f)) * (1.0f/1.375f);
        sFeat[pr][f] = __expf(-z*z);
      }
    }
    __syncthreads();
    // ---- S3: per-wave partial dot with register-resident weights ----
    {
      float acc0 = 0.0f, acc1 = 0.0f;
      if (w == 0){
        if (sSame[0]) acc0 = W_rel[sRel[0]*64 + lane];
        if (sSame[1]) acc1 = W_rel[sRel[1]*64 + lane];
      }
      const float* f0p = &sFeat[0][w*FCHUNK];
      const float* f1p = &sFeat[1][w*FCHUNK];
      #pragma unroll
      for (int i = 0; i < FCHUNK; ++i){
        acc0 += f0p[i] * Wreg[i];
        acc1 += f1p[i] * Wreg[i];
      }
      sPart[0][w][lane] = acc0;
      sPart[1][w][lane] = acc1;
    }
    __syncthreads();
    // ---- S4: reduce partials + LayerNorm (wave 0 -> pair 0, wave 1 -> pair 1) ----
    if (tid < 128){
      int pr = w;
      float x = sPart[pr][0][lane] + sPart[pr][1][lane]
              + sPart[pr][2][lane] + sPart[pr][3][lane];
      float s = x;
      #pragma unroll
      for (int off = 32; off > 0; off >>= 1) s += __shfl_xor(s, off, 64);
      float mu  = s * (1.0f/64.0f);
      float dxm = x - mu;
      float s2 = dxm*dxm;
      #pragma unroll
      for (int off = 32; off > 0; off >>= 1) s2 += __shfl_xor(s2, off, 64);
      float inv = rsqrtf(s2*(1.0f/64.0f) + 1e-5f);
      sXv[pr][lane] = lng * dxm * inv + lnb;
    }
    __syncthreads();
    // ---- S5: h = gelu(x @ W1 + b1), 2 pairs x 128 ch across 256 threads ----
    {
      int pr = tid >> 7;
      int jj = tid & 127;
      float acc = b1v;
      #pragma unroll
      for (int p = 0; p < 64; ++p)
        acc += sXv[pr][p] * bf16tof(sW1h[p*128 + jj]);
      sH[pr][jj] = fast_gelu(acc);
    }
    __syncthreads();
    // ---- S6: out partials = h @ W2 (split j-range in halves) ----
    {
      int pr   = (tid >> 6) & 1;
      int half = tid >> 7;
      float acc = 0.0f;
      #pragma unroll
      for (int q = 0; q < 64; ++q){
        int jj = half*64 + q;
        acc += sH[pr][jj] * bf16tof(sW2h[jj*64 + lane]);
      }
      sOutP[half][pr][lane] = acc;
    }
    __syncthreads();
    // ---- S7: combine + store ----
    if (tid < 128){
      int pr = w;
      float o = b2v + sOutP[0][pr][lane] + sOutP[1][pr][lane];
      out[((size_t)n*K_ + (size_t)(k0 + pr))*64 + lane] = o;
    }
    // no barrier needed: next S0 writes touch disjoint LDS arrays.
  }
}

extern "C" void kernel_launch(void* const* d_in, const int* in_sizes, int n_in,
                              void* d_out, int out_size, void* d_ws, size_t ws_size,
                              hipStream_t stream) {
  (void)in_sizes; (void)n_in; (void)out_size; (void)d_ws; (void)ws_size;
  const float* pos    = (const float*)d_in[0];
  const float* dmap   = (const float*)d_in[1];
  const int*   nbr    = (const int*)  d_in[2];
  const int*   resi   = (const int*)  d_in[3];
  const int*   chain  = (const int*)  d_in[4];
  const int*   batch  = (const int*)  d_in[5];
  const float* mask   = (const float*)d_in[6];
  const float* W_rel  = (const float*)d_in[7];
  const float* W_dmap = (const float*)d_in[8];
  const float* W_dist = (const float*)d_in[9];
  const float* W_dir  = (const float*)d_in[10];
  const float* W_rot  = (const float*)d_in[11];
  const float* W_vec  = (const float*)d_in[12];
  const float* ln_g   = (const float*)d_in[13];
  const float* ln_b   = (const float*)d_in[14];
  const float* W1     = (const float*)d_in[15];
  const float* b1     = (const float*)d_in[16];
  const float* W2     = (const float*)d_in[17];
  const float* b2     = (const float*)d_in[18];
  float* out = (float*)d_out;

  dsd_kernel<<<dim3(N_), dim3(256), 0, stream>>>(
      pos, dmap, nbr, resi, chain, batch, mask,
      W_rel, W_dmap, W_dist, W_dir, W_rot, W_vec,
      ln_g, ln_b, W1, b1, W2, b2, out);
}

// Round 2
// 551.406 us; speedup vs baseline: 4.2269x; 4.2269x over previous
//
#include <hip/hip_runtime.h>
#include <cstdint>
#include <cstddef>

#define NN 8192
#define KK 32

typedef __bf16 bf16x8 __attribute__((ext_vector_type(8)));
typedef float  f32x4  __attribute__((ext_vector_type(4)));

union U4B { uint4 u; bf16x8 h; };
__device__ __forceinline__ bf16x8 asbf(uint4 u){ U4B v; v.u = u; return v.h; }

__device__ __forceinline__ unsigned short ftobf16(float f){
  union { float f; unsigned int i; } v; v.f = f;
  unsigned int x = v.i;
  x += 0x7fffu + ((x >> 16) & 1u);   // RNE
  return (unsigned short)(x >> 16);
}
__device__ __forceinline__ float fast_gelu(float x){
  float y = 0.7978845608028654f * (x + 0.044715f * x * x * x);
  float e = __expf(2.0f * y);
  float t = 1.0f - 2.0f / (e + 1.0f);
  return 0.5f * x * (1.0f + t);
}

struct Frame { float e[9]; float t[3]; };
__device__ __forceinline__ Frame calc_frame(const float* p){
  Frame fr;
  float tx=p[3], ty=p[4], tz=p[5];
  float v1x=p[6]-tx, v1y=p[7]-ty, v1z=p[8]-tz;
  float v2x=p[0]-tx, v2y=p[1]-ty, v2z=p[2]-tz;
  float n1 = sqrtf(v1x*v1x+v1y*v1y+v1z*v1z) + 1e-6f;
  float e1x=v1x/n1, e1y=v1y/n1, e1z=v1z/n1;
  float dp = v2x*e1x+v2y*e1y+v2z*e1z;
  float ux=v2x-dp*e1x, uy=v2y-dp*e1y, uz=v2z-dp*e1z;
  float n2 = sqrtf(ux*ux+uy*uy+uz*uz) + 1e-6f;
  float e2x=ux/n2, e2y=uy/n2, e2z=uz/n2;
  fr.e[0]=e1x; fr.e[1]=e1y; fr.e[2]=e1z;
  fr.e[3]=e2x; fr.e[4]=e2y; fr.e[5]=e2z;
  fr.e[6]=e1y*e2z - e1z*e2y;
  fr.e[7]=e1z*e2x - e1x*e2z;
  fr.e[8]=e1x*e2y - e1y*e2x;
  fr.t[0]=tx; fr.t[1]=ty; fr.t[2]=tz;
  return fr;
}

// ---- prologue: weights -> bf16, B-operand (transposed) layouts in ws ----
// ws:  Wt[64][488]  (Wt[p][k] = Wcat[k][p], k>=455 -> 0)
//      W1t[128][64] (W1t[j][p] = W1[p][j])
//      W2t[64][128] (W2t[p][j] = W2[j][p])
__global__ void prep_w(const float* __restrict__ W_dmap, const float* __restrict__ W_dist,
    const float* __restrict__ W_dir, const float* __restrict__ W_rot,
    const float* __restrict__ W_vec, const float* __restrict__ W1,
    const float* __restrict__ W2, unsigned short* __restrict__ ws)
{
  int idx = blockIdx.x*256 + threadIdx.x;
  if (idx < 64*488){
    int p = idx / 488, k = idx - p*488;
    float v = 0.0f;
    if      (k < 400) v = W_dist[k*64+p];
    else if (k < 416) v = W_dmap[(k-400)*64+p];
    else if (k < 431) v = W_dir[(k-416)*64+p];
    else if (k < 446) v = W_vec[(k-431)*64+p];
    else if (k < 455) v = W_rot[(k-446)*64+p];
    ws[idx] = ftobf16(v);
  } else if (idx < 64*488 + 128*64){
    int i = idx - 64*488; int j = i>>6, p = i&63;
    ws[idx] = ftobf16(W1[p*128+j]);
  } else if (idx < 64*488 + 128*64 + 64*128){
    int i = idx - (64*488 + 128*64); int p = i>>7, j = i&127;
    ws[idx] = ftobf16(W2[j*64+p]);
  }
}

__global__ __launch_bounds__(256, 2)
void dsd_mfma(const float* __restrict__ pos, const float* __restrict__ dmap,
    const int* __restrict__ nbr, const int* __restrict__ resi,
    const int* __restrict__ chain, const int* __restrict__ batch,
    const float* __restrict__ mask,
    const float* __restrict__ W_rel,
    const float* __restrict__ ln_g, const float* __restrict__ ln_b,
    const float* __restrict__ b1, const float* __restrict__ b2,
    const unsigned short* __restrict__ wt,
    const unsigned short* __restrict__ w1t,
    const unsigned short* __restrict__ w2t,
    float* __restrict__ out)
{
  __shared__ __align__(16) unsigned short sFeat[32][488]; // bf16 features, A-layout
  __shared__ __align__(16) unsigned short sXA[32][72];    // bf16 post-LN x
  __shared__ __align__(16) unsigned short sH[32][136];    // bf16 hidden
  __shared__ __align__(16) float x32[32][68];             // fp32 pre-LN
  __shared__ float sPosJ[32][16];
  __shared__ float sD[32][25];
  __shared__ float sPosI[15];
  __shared__ float sFrN[12];
  __shared__ float sLnG[64], sLnB[64], sB1[128], sB2[64];
  __shared__ int   sJ[32], sRel[32];
  __shared__ float sSame[32], sPm[32], sDv[32];

  const int tid  = threadIdx.x;
  const int w    = tid >> 6;
  const int lane = tid & 63;
  const int l15  = lane & 15;
  const int q    = lane >> 4;
  const int n    = blockIdx.x;
  const int mt   = w & 1;     // m-tile for MLP phases
  const int ng   = w >> 1;    // n-tile group for MLP phases

  // ---- persistent B-fragments (global, L2-hot; latency hidden by feature gen) ----
  uint4 pB[15];
  {
    const unsigned short* rowp = wt + (size_t)(w*16 + l15)*488 + q*8;
    #pragma unroll
    for (int kk=0; kk<15; ++kk) pB[kk] = *(const uint4*)(rowp + kk*32);
  }
  uint4 b1B[4][2];
  #pragma unroll
  for (int t=0;t<4;++t){
    const unsigned short* rowp = w1t + (size_t)((ng*4+t)*16 + l15)*64 + q*8;
    #pragma unroll
    for (int kk=0;kk<2;++kk) b1B[t][kk] = *(const uint4*)(rowp + kk*32);
  }
  uint4 b2B[2][4];
  #pragma unroll
  for (int t=0;t<2;++t){
    const unsigned short* rowp = w2t + (size_t)((ng*2+t)*16 + l15)*128 + q*8;
    #pragma unroll
    for (int kk=0;kk<4;++kk) b2B[t][kk] = *(const uint4*)(rowp + kk*32);
  }

  // ---- stage A: per-pair scalars, pos_i, frame_n, small tables ----
  if (tid < 32){
    int nb = nbr[n*KK + tid];
    int valid = (nb != -1) ? 1 : 0;
    int j = nb < 0 ? 0 : nb;
    sJ[tid] = j;
    int rl = resi[j] - resi[n];
    rl = rl < -32 ? -32 : (rl > 32 ? 32 : rl);
    sRel[tid] = rl + 32;
    sSame[tid] = (chain[j]==chain[n] && batch[j]==batch[n]) ? 1.0f : 0.0f;
    float pm = mask[n]*mask[j]*(float)valid;
    sPm[tid] = pm;
    sDv[tid] = dmap[(size_t)n*NN + j];
    out[(size_t)NN*KK*64 + (size_t)n*KK + tid] = pm;
  } else if (tid < 47){
    sPosI[tid-32] = pos[n*15 + (tid-32)];
  } else if (tid == 47){
    float pl[9];
    #pragma unroll
    for (int i=0;i<9;++i) pl[i] = pos[n*15+i];
    Frame fr = calc_frame(pl);
    #pragma unroll
    for (int i=0;i<9;++i) sFrN[i] = fr.e[i];
    #pragma unroll
    for (int i=0;i<3;++i) sFrN[9+i] = fr.t[i];
  } else if (tid >= 64 && tid < 192){
    sB1[tid-64] = b1[tid-64];
  } else if (tid >= 192){
    sB2[tid-192] = b2[tid-192];
  }
  if (tid < 64){ sLnG[tid] = ln_g[tid]; sLnB[tid] = ln_b[tid]; }
  __syncthreads();

  // ---- stage B: neighbor positions + W_rel prefetch ----
  #pragma unroll
  for (int t=0;t<2;++t){
    int e = tid + t*256;
    int pair = e >> 4, qq = e & 15;
    if (qq < 15) sPosJ[pair][qq] = pos[sJ[pair]*15 + qq];
  }
  float wr0[4], wr1[4];
  #pragma unroll
  for (int r=0;r<4;++r){
    int p0 = q*4+r, p1 = 16+q*4+r;
    int pc = w*16 + l15;
    wr0[r] = (sSame[p0] != 0.0f) ? W_rel[sRel[p0]*64 + pc] : 0.0f;
    wr1[r] = (sSame[p1] != 0.0f) ? W_rel[sRel[p1]*64 + pc] : 0.0f;
  }
  __syncthreads();

  // ---- stage C: dir/vec, rot, distances, zero-pad ----
  {
    int pair = tid >> 3, a = tid & 7;
    if (a < 5){
      float x0 = sPosJ[pair][a*3+0] - sFrN[9];
      float x1 = sPosJ[pair][a*3+1] - sFrN[10];
      float x2 = sPosJ[pair][a*3+2] - sFrN[11];
      float r0 = sFrN[0]*x0 + sFrN[1]*x1 + sFrN[2]*x2;
      float r1 = sFrN[3]*x0 + sFrN[4]*x1 + sFrN[5]*x2;
      float r2 = sFrN[6]*x0 + sFrN[7]*x1 + sFrN[8]*x2;
      float inv = 1.0f/(sqrtf(r0*r0+r1*r1+r2*r2)+1e-6f);
      sFeat[pair][416+a*3+0] = ftobf16(r0*inv);
      sFeat[pair][416+a*3+1] = ftobf16(r1*inv);
      sFeat[pair][416+a*3+2] = ftobf16(r2*inv);
      sFeat[pair][431+a*3+0] = ftobf16(r0*0.1f);
      sFeat[pair][431+a*3+1] = ftobf16(r1*0.1f);
      sFeat[pair][431+a*3+2] = ftobf16(r2*0.1f);
    }
  }
  if (tid < 32){
    Frame fj = calc_frame(sPosJ[tid]);
    #pragma unroll
    for (int i=0;i<3;++i)
      #pragma unroll
      for (int l=0;l<3;++l)
        sFeat[tid][446+i*3+l] = ftobf16(
          sFrN[i*3+0]*fj.e[l*3+0] + sFrN[i*3+1]*fj.e[l*3+1] + sFrN[i*3+2]*fj.e[l*3+2]);
  }
  #pragma unroll
  for (int t=0;t<4;++t){
    int e = tid + t*256;
    int pair = e >> 5, ab = e & 31;
    if (ab < 25){
      int a = ab/5, b = ab - (ab/5)*5;
      float dx = sPosI[a*3+0] - sPosJ[pair][b*3+0];
      float dy = sPosI[a*3+1] - sPosJ[pair][b*3+1];
      float dz = sPosI[a*3+2] - sPosJ[pair][b*3+2];
      sD[pair][ab] = sqrtf(dx*dx+dy*dy+dz*dz);
      sFeat[pair][455+ab] = 0;   // zero pad k in [455,480)
    }
  }
  __syncthreads();

  // ---- stage D: RBF expansion (dist 400/pair, dmap 16/pair) ----
  for (int t=0;t<25;++t){
    int e = tid + t*256;             // e < 6400 = 32*25*8
    int pair = e / 200;
    int rem  = e - pair*200;
    int ab = rem >> 3, cp = rem & 7;
    float d = sD[pair][ab];
    float z0 = (d - (float)(2*cp  )*(22.0f/15.0f)) * (1.0f/1.375f);
    float z1 = (d - (float)(2*cp+1)*(22.0f/15.0f)) * (1.0f/1.375f);
    unsigned int u0 = ftobf16(__expf(-z0*z0));
    unsigned int u1 = ftobf16(__expf(-z1*z1));
    *(unsigned int*)&sFeat[pair][ab*16 + cp*2] = u0 | (u1<<16);
  }
  #pragma unroll
  for (int t=0;t<2;++t){
    int e = tid + t*256;
    int pair = e >> 4, c = e & 15;
    float z = (sDv[pair] - (float)c*(22.0f/15.0f)) * (1.0f/1.375f);
    float v = (sPm[pair] > 0.0f) ? __expf(-z*z) : 0.0f;
    sFeat[pair][400+c] = ftobf16(v);
  }
  __syncthreads();

  // ---- projection: [32x480] @ [480x64], wave w owns p-tile w ----
  f32x4 acc0 = {0.f,0.f,0.f,0.f}, acc1 = {0.f,0.f,0.f,0.f};
  {
    const unsigned short* a0p = &sFeat[l15][q*8];
    const unsigned short* a1p = &sFeat[16+l15][q*8];
    #pragma unroll
    for (int kk=0; kk<15; ++kk){
      bf16x8 A0 = asbf(*(const uint4*)(a0p + kk*32));
      bf16x8 A1 = asbf(*(const uint4*)(a1p + kk*32));
      bf16x8 B  = asbf(pB[kk]);
      acc0 = __builtin_amdgcn_mfma_f32_16x16x32_bf16(A0, B, acc0, 0,0,0);
      acc1 = __builtin_amdgcn_mfma_f32_16x16x32_bf16(A1, B, acc1, 0,0,0);
    }
  }
  {
    int pc = w*16 + l15;
    #pragma unroll
    for (int r=0;r<4;++r){
      x32[q*4+r][pc]    = acc0[r] + wr0[r];
      x32[16+q*4+r][pc] = acc1[r] + wr1[r];
    }
  }
  __syncthreads();

  // ---- LayerNorm: 8 threads per pair ----
  {
    int pair = tid >> 3, g = tid & 7;
    float4 xa = *(const float4*)&x32[pair][g*8];
    float4 xb = *(const float4*)&x32[pair][g*8+4];
    float vals[8] = {xa.x,xa.y,xa.z,xa.w, xb.x,xb.y,xb.z,xb.w};
    float s = 0.f, s2 = 0.f;
    #pragma unroll
    for (int i=0;i<8;++i){ s += vals[i]; s2 += vals[i]*vals[i]; }
    #pragma unroll
    for (int o=1;o<8;o<<=1){ s += __shfl_xor(s,o,64); s2 += __shfl_xor(s2,o,64); }
    float mu  = s  * (1.0f/64.0f);
    float var = s2 * (1.0f/64.0f) - mu*mu;
    float inv = rsqrtf(var + 1e-5f);
    unsigned int pk[4];
    #pragma unroll
    for (int i=0;i<4;++i){
      int p0 = g*8 + 2*i;
      float v0 = sLnG[p0  ]*(vals[2*i  ]-mu)*inv + sLnB[p0  ];
      float v1 = sLnG[p0+1]*(vals[2*i+1]-mu)*inv + sLnB[p0+1];
      pk[i] = (unsigned int)ftobf16(v0) | ((unsigned int)ftobf16(v1)<<16);
    }
    uint4 pkv; pkv.x=pk[0]; pkv.y=pk[1]; pkv.z=pk[2]; pkv.w=pk[3];
    *(uint4*)&sXA[pair][g*8] = pkv;
  }
  __syncthreads();

  // ---- MLP layer 1: [32x64]@[64x128], gelu ----
  f32x4 hacc[4];
  #pragma unroll
  for (int t=0;t<4;++t){ hacc[t][0]=0.f; hacc[t][1]=0.f; hacc[t][2]=0.f; hacc[t][3]=0.f; }
  {
    const unsigned short* ap = &sXA[mt*16 + l15][q*8];
    #pragma unroll
    for (int kk=0;kk<2;++kk){
      bf16x8 A = asbf(*(const uint4*)(ap + kk*32));
      #pragma unroll
      for (int t=0;t<4;++t)
        hacc[t] = __builtin_amdgcn_mfma_f32_16x16x32_bf16(A, asbf(b1B[t][kk]), hacc[t], 0,0,0);
    }
  }
  #pragma unroll
  for (int t=0;t<4;++t){
    int j = (ng*4+t)*16 + l15;
    float bb = sB1[j];
    #pragma unroll
    for (int r=0;r<4;++r){
      int m = mt*16 + q*4 + r;
      sH[m][j] = ftobf16(fast_gelu(hacc[t][r] + bb));
    }
  }
  __syncthreads();

  // ---- MLP layer 2: [32x128]@[128x64], +b2, store ----
  f32x4 oacc[2];
  #pragma unroll
  for (int t=0;t<2;++t){ oacc[t][0]=0.f; oacc[t][1]=0.f; oacc[t][2]=0.f; oacc[t][3]=0.f; }
  {
    const unsigned short* ap = &sH[mt*16 + l15][q*8];
    #pragma unroll
    for (int kk=0;kk<4;++kk){
      bf16x8 A = asbf(*(const uint4*)(ap + kk*32));
      #pragma unroll
      for (int t=0;t<2;++t)
        oacc[t] = __builtin_amdgcn_mfma_f32_16x16x32_bf16(A, asbf(b2B[t][kk]), oacc[t], 0,0,0);
    }
  }
  #pragma unroll
  for (int t=0;t<2;++t){
    int p = (ng*2+t)*16 + l15;
    float bb = sB2[p];
    #pragma unroll
    for (int r=0;r<4;++r){
      int m = mt*16 + q*4 + r;
      out[((size_t)n*KK + m)*64 + p] = oacc[t][r] + bb;
    }
  }
}

extern "C" void kernel_launch(void* const* d_in, const int* in_sizes, int n_in,
                              void* d_out, int out_size, void* d_ws, size_t ws_size,
                              hipStream_t stream) {
  (void)in_sizes; (void)n_in; (void)out_size; (void)ws_size;
  const float* pos    = (const float*)d_in[0];
  const float* dmap   = (const float*)d_in[1];
  const int*   nbr    = (const int*)  d_in[2];
  const int*   resi   = (const int*)  d_in[3];
  const int*   chain  = (const int*)  d_in[4];
  const int*   batch  = (const int*)  d_in[5];
  const float* mask   = (const float*)d_in[6];
  const float* W_rel  = (const float*)d_in[7];
  const float* W_dmap = (const float*)d_in[8];
  const float* W_dist = (const float*)d_in[9];
  const float* W_dir  = (const float*)d_in[10];
  const float* W_rot  = (const float*)d_in[11];
  const float* W_vec  = (const float*)d_in[12];
  const float* ln_g   = (const float*)d_in[13];
  const float* ln_b   = (const float*)d_in[14];
  const float* W1     = (const float*)d_in[15];
  const float* b1     = (const float*)d_in[16];
  const float* W2     = (const float*)d_in[17];
  const float* b2     = (const float*)d_in[18];
  float* out = (float*)d_out;

  unsigned short* wt  = (unsigned short*)d_ws;
  unsigned short* w1t = wt + 64*488;
  unsigned short* w2t = w1t + 128*64;

  prep_w<<<dim3(186), dim3(256), 0, stream>>>(W_dmap, W_dist, W_dir, W_rot, W_vec, W1, W2, wt);
  dsd_mfma<<<dim3(NN), dim3(256), 0, stream>>>(
      pos, dmap, nbr, resi, chain, batch, mask, W_rel,
      ln_g, ln_b, b1, b2, wt, w1t, w2t, out);
}

// Round 3
// 466.839 us; speedup vs baseline: 4.9926x; 1.1811x over previous
//
#include <hip/hip_runtime.h>
#include <hip/hip_bf16.h>
#include <cstdint>
#include <cstddef>

#define NN 8192
#define KK 32

typedef __bf16 bf16x8 __attribute__((ext_vector_type(8)));
typedef float  f32x4  __attribute__((ext_vector_type(4)));

union U4B { uint4 u; bf16x8 h; };
__device__ __forceinline__ bf16x8 asbf(uint4 u){ U4B v; v.u = u; return v.h; }

__device__ __forceinline__ unsigned short ftobf16(float f){
  union { float f; unsigned int i; } v; v.f = f;
  unsigned int x = v.i;
  x += 0x7fffu + ((x >> 16) & 1u);   // RNE
  return (unsigned short)(x >> 16);
}
__device__ __forceinline__ unsigned int pk_bf16(float a, float b){
  union { __hip_bfloat162 h; unsigned int u; } v;
  v.h = __float22bfloat162_rn(float2{a, b});
  return v.u;
}
__device__ __forceinline__ float exp2n(float u){   // exp2(-u)
#if __has_builtin(__builtin_amdgcn_exp2f)
  return __builtin_amdgcn_exp2f(-u);
#else
  return exp2f(-u);
#endif
}
__device__ __forceinline__ float fast_gelu(float x){
  float y = 0.7978845608028654f * (x + 0.044715f * x * x * x);
  float e = __expf(2.0f * y);
  float t = 1.0f - 2.0f / (e + 1.0f);
  return 0.5f * x * (1.0f + t);
}

struct Frame { float e[9]; float t[3]; };
__device__ __forceinline__ Frame calc_frame(const float* p){
  Frame fr;
  float tx=p[3], ty=p[4], tz=p[5];
  float v1x=p[6]-tx, v1y=p[7]-ty, v1z=p[8]-tz;
  float v2x=p[0]-tx, v2y=p[1]-ty, v2z=p[2]-tz;
  float n1 = sqrtf(v1x*v1x+v1y*v1y+v1z*v1z) + 1e-6f;
  float e1x=v1x/n1, e1y=v1y/n1, e1z=v1z/n1;
  float dp = v2x*e1x+v2y*e1y+v2z*e1z;
  float ux=v2x-dp*e1x, uy=v2y-dp*e1y, uz=v2z-dp*e1z;
  float n2 = sqrtf(ux*ux+uy*uy+uz*uz) + 1e-6f;
  float e2x=ux/n2, e2y=uy/n2, e2z=uz/n2;
  fr.e[0]=e1x; fr.e[1]=e1y; fr.e[2]=e1z;
  fr.e[3]=e2x; fr.e[4]=e2y; fr.e[5]=e2z;
  fr.e[6]=e1y*e2z - e1z*e2y;
  fr.e[7]=e1z*e2x - e1x*e2z;
  fr.e[8]=e1x*e2y - e1y*e2x;
  fr.t[0]=tx; fr.t[1]=ty; fr.t[2]=tz;
  return fr;
}

// ---- prologue: weights -> bf16, B-operand (transposed) layouts in ws ----
__global__ void prep_w(const float* __restrict__ W_dmap, const float* __restrict__ W_dist,
    const float* __restrict__ W_dir, const float* __restrict__ W_rot,
    const float* __restrict__ W_vec, const float* __restrict__ W1,
    const float* __restrict__ W2, unsigned short* __restrict__ ws)
{
  int idx = blockIdx.x*256 + threadIdx.x;
  if (idx < 64*488){
    int p = idx / 488, k = idx - p*488;
    float v = 0.0f;
    if      (k < 400) v = W_dist[k*64+p];
    else if (k < 416) v = W_dmap[(k-400)*64+p];
    else if (k < 431) v = W_dir[(k-416)*64+p];
    else if (k < 446) v = W_vec[(k-431)*64+p];
    else if (k < 455) v = W_rot[(k-446)*64+p];
    ws[idx] = ftobf16(v);
  } else if (idx < 64*488 + 128*64){
    int i = idx - 64*488; int j = i>>6, p = i&63;
    ws[idx] = ftobf16(W1[p*128+j]);
  } else if (idx < 64*488 + 128*64 + 64*128){
    int i = idx - (64*488 + 128*64); int p = i>>7, j = i&127;
    ws[idx] = ftobf16(W2[j*64+p]);
  }
}

// RBF folding: exp(-z^2), z=(d-c*DELTA)/SIGMA  ==  exp2(-w^2), w = d*K1 - c*K2
// K1 = sqrt(log2 e)/SIGMA, K2 = DELTA*K1
#define RBF_K1 0.8735435700f
#define RBF_K2 1.2811972361f

__global__ __launch_bounds__(256, 4)
void dsd_mfma(const float* __restrict__ pos, const float* __restrict__ dmap,
    const int* __restrict__ nbr, const int* __restrict__ resi,
    const int* __restrict__ chain, const int* __restrict__ batch,
    const float* __restrict__ mask,
    const float* __restrict__ W_rel,
    const float* __restrict__ ln_g, const float* __restrict__ ln_b,
    const float* __restrict__ b1, const float* __restrict__ b2,
    const unsigned short* __restrict__ wt,
    const unsigned short* __restrict__ w1t,
    const unsigned short* __restrict__ w2t,
    float* __restrict__ out)
{
  __shared__ __align__(16) unsigned short sFeat[32][488]; // bf16 features, A-layout
  __shared__ __align__(16) float2 sLNp[32][4];            // (sum,sumsq) per (row,wave)
  __shared__ __align__(16) float sPosJ[32][16];
  __shared__ float sD[32][25];
  __shared__ float sPosI[15];
  __shared__ float sFrN[12];
  __shared__ float sB1[128];
  __shared__ float sB2[64];
  __shared__ int   sRel[32];
  __shared__ float sSame[32], sPm[32], sDv[32];

  // aliases into sFeat (dead after projection; barrier-separated)
  unsigned short (*sXA)[72]  = (unsigned short(*)[72])(&sFeat[0][0]);            // 4608 B
  unsigned short (*sH)[136]  = (unsigned short(*)[136])(&sFeat[0][0] + 2304);    // 8704 B

  const int tid  = threadIdx.x;
  const int w    = tid >> 6;
  const int lane = tid & 63;
  const int l15  = lane & 15;
  const int q    = lane >> 4;
  const int n    = blockIdx.x;
  const int mt   = w & 1;
  const int ng   = w >> 1;
  const int g    = tid & 7;
  const int pairD= tid >> 3;

  const float lng = ln_g[w*16 + l15];
  const float lnb = ln_b[w*16 + l15];

  // ---- persistent projection B-fragments ----
  uint4 pB[15];
  {
    const unsigned short* rowp = wt + (size_t)(w*16 + l15)*488 + q*8;
    #pragma unroll
    for (int kk=0; kk<15; ++kk) pB[kk] = *(const uint4*)(rowp + kk*32);
  }

  // ---- stage A ----
  if (tid < 32){
    int nb = nbr[n*KK + tid];
    int valid = (nb != -1) ? 1 : 0;
    int j = nb < 0 ? 0 : nb;
    int rl = resi[j] - resi[n];
    rl = rl < -32 ? -32 : (rl > 32 ? 32 : rl);
    sRel[tid] = rl + 32;
    sSame[tid] = (chain[j]==chain[n] && batch[j]==batch[n]) ? 1.0f : 0.0f;
    float pm = mask[n]*mask[j]*(float)valid;
    sPm[tid] = pm;
    sDv[tid] = dmap[(size_t)n*NN + j];
    out[(size_t)NN*KK*64 + (size_t)n*KK + tid] = pm;
    const float* pj = pos + (size_t)j*15;
    #pragma unroll
    for (int qq=0; qq<15; ++qq) sPosJ[tid][qq] = pj[qq];
  } else if (tid < 47){
    sPosI[tid-32] = pos[n*15 + (tid-32)];
  } else if (tid == 47){
    float pl[9];
    #pragma unroll
    for (int i=0;i<9;++i) pl[i] = pos[n*15+i];
    Frame fr = calc_frame(pl);
    #pragma unroll
    for (int i=0;i<9;++i) sFrN[i] = fr.e[i];
    #pragma unroll
    for (int i=0;i<3;++i) sFrN[9+i] = fr.t[i];
  } else if (tid >= 64 && tid < 192){
    sB1[tid-64] = b1[tid-64];
  } else if (tid >= 192){
    sB2[tid-192] = b2[tid-192];
  }
  __syncthreads();   // #1

  // ---- W_rel gather (used in proj epilogue; long slack) ----
  float wr0[4], wr1[4];
  {
    int pc = w*16 + l15;
    #pragma unroll
    for (int r=0;r<4;++r){
      int p0 = q*4+r, p1 = 16+q*4+r;
      wr0[r] = sSame[p0] * W_rel[sRel[p0]*64 + pc];
      wr1[r] = sSame[p1] * W_rel[sRel[p1]*64 + pc];
    }
  }

  // ---- stage C: dirs/vec (8 thr/pair), rot (tid<32), distances+pad ----
  if (g < 5){
    int a = g;
    float x0 = sPosJ[pairD][a*3+0] - sFrN[9];
    float x1 = sPosJ[pairD][a*3+1] - sFrN[10];
    float x2 = sPosJ[pairD][a*3+2] - sFrN[11];
    float r0 = sFrN[0]*x0 + sFrN[1]*x1 + sFrN[2]*x2;
    float r1 = sFrN[3]*x0 + sFrN[4]*x1 + sFrN[5]*x2;
    float r2 = sFrN[6]*x0 + sFrN[7]*x1 + sFrN[8]*x2;
    float inv = 1.0f/(sqrtf(r0*r0+r1*r1+r2*r2)+1e-6f);
    sFeat[pairD][416+a*3+0] = ftobf16(r0*inv);
    sFeat[pairD][416+a*3+1] = ftobf16(r1*inv);
    sFeat[pairD][416+a*3+2] = ftobf16(r2*inv);
    sFeat[pairD][431+a*3+0] = ftobf16(r0*0.1f);
    sFeat[pairD][431+a*3+1] = ftobf16(r1*0.1f);
    sFeat[pairD][431+a*3+2] = ftobf16(r2*0.1f);
  }
  if (tid < 32){
    Frame fj = calc_frame(sPosJ[tid]);
    #pragma unroll
    for (int i=0;i<3;++i)
      #pragma unroll
      for (int l=0;l<3;++l)
        sFeat[tid][446+i*3+l] = ftobf16(
          sFrN[i*3+0]*fj.e[l*3+0] + sFrN[i*3+1]*fj.e[l*3+1] + sFrN[i*3+2]*fj.e[l*3+2]);
  }
  #pragma unroll
  for (int t=0;t<4;++t){
    int e = tid + t*256;
    int pair = e >> 5, ab = e & 31;
    if (ab < 25){
      int a = ab/5, b = ab - (ab/5)*5;
      float dx = sPosI[a*3+0] - sPosJ[pair][b*3+0];
      float dy = sPosI[a*3+1] - sPosJ[pair][b*3+1];
      float dz = sPosI[a*3+2] - sPosJ[pair][b*3+2];
      sD[pair][ab] = sqrtf(dx*dx+dy*dy+dz*dz);
      sFeat[pair][455+ab] = 0;   // zero pad k in [455,480)
    }
  }
  __syncthreads();   // #2

  // ---- stage D: RBF expansion, div-free, 2 values/thread/iter ----
  {
    const float c0k = (float)(2*g  ) * RBF_K2;
    const float c1k = (float)(2*g+1) * RBF_K2;
    unsigned short* frow = &sFeat[pairD][2*g];
    #pragma unroll
    for (int t=0;t<25;++t){
      float dp = sD[pairD][t] * RBF_K1;
      float w0 = dp - c0k, w1 = dp - c1k;
      *(unsigned int*)(frow + t*16) = pk_bf16(exp2n(w0*w0), exp2n(w1*w1));
    }
    float dp = sDv[pairD] * RBF_K1;
    float w0 = dp - c0k, w1 = dp - c1k;
    float e0 = exp2n(w0*w0), e1 = exp2n(w1*w1);
    if (!(sPm[pairD] > 0.0f)){ e0 = 0.0f; e1 = 0.0f; }
    *(unsigned int*)(frow + 400) = pk_bf16(e0, e1);
  }
  __syncthreads();   // #3

  // ---- projection: [32x480] @ [480x64], wave w owns p-tile w ----
  f32x4 acc0 = {0.f,0.f,0.f,0.f}, acc1 = {0.f,0.f,0.f,0.f};
  {
    const unsigned short* a0p = &sFeat[l15][q*8];
    const unsigned short* a1p = &sFeat[16+l15][q*8];
    #pragma unroll
    for (int kk=0; kk<15; ++kk){
      bf16x8 A0 = asbf(*(const uint4*)(a0p + kk*32));
      bf16x8 A1 = asbf(*(const uint4*)(a1p + kk*32));
      bf16x8 B  = asbf(pB[kk]);
      acc0 = __builtin_amdgcn_mfma_f32_16x16x32_bf16(A0, B, acc0, 0,0,0);
      acc1 = __builtin_amdgcn_mfma_f32_16x16x32_bf16(A1, B, acc1, 0,0,0);
    }
  }
  #pragma unroll
  for (int r=0;r<4;++r){ acc0[r] += wr0[r]; acc1[r] += wr1[r]; }

  // ---- MLP B-fragments (pB dead now; L2-hot; latency hidden by LN) ----
  uint4 b1B[4][2];
  #pragma unroll
  for (int t=0;t<4;++t){
    const unsigned short* rowp = w1t + (size_t)((ng*4+t)*16 + l15)*64 + q*8;
    #pragma unroll
    for (int kk=0;kk<2;++kk) b1B[t][kk] = *(const uint4*)(rowp + kk*32);
  }
  uint4 b2B[2][4];
  #pragma unroll
  for (int t=0;t<2;++t){
    const unsigned short* rowp = w2t + (size_t)((ng*2+t)*16 + l15)*128 + q*8;
    #pragma unroll
    for (int kk=0;kk<4;++kk) b2B[t][kk] = *(const uint4*)(rowp + kk*32);
  }

  // ---- LN partials: butterfly over the 16-lane col group ----
  {
    float s0[4], v0[4], s1[4], v1[4];
    #pragma unroll
    for (int r=0;r<4;++r){
      s0[r]=acc0[r]; v0[r]=acc0[r]*acc0[r];
      s1[r]=acc1[r]; v1[r]=acc1[r]*acc1[r];
    }
    #pragma unroll
    for (int off=1; off<16; off<<=1){
      #pragma unroll
      for (int r=0;r<4;++r){
        s0[r] += __shfl_xor(s0[r], off, 64);
        v0[r] += __shfl_xor(v0[r], off, 64);
        s1[r] += __shfl_xor(s1[r], off, 64);
        v1[r] += __shfl_xor(v1[r], off, 64);
      }
    }
    if (l15 == 0){
      #pragma unroll
      for (int r=0;r<4;++r){
        sLNp[q*4+r][w]    = float2{s0[r], v0[r]};
        sLNp[16+q*4+r][w] = float2{s1[r], v1[r]};
      }
    }
  }
  __syncthreads();   // #4  (also fences: all sFeat reads done before sXA writes)

  // ---- finish LN, write normalized bf16 x into sXA (aliased) ----
  #pragma unroll
  for (int r=0;r<4;++r){
    {
      int m = q*4+r;
      float4 pa = *(const float4*)&sLNp[m][0];
      float4 pb = *(const float4*)&sLNp[m][2];
      float s  = pa.x + pa.z + pb.x + pb.z;
      float s2 = pa.y + pa.w + pb.y + pb.w;
      float mu = s * (1.0f/64.0f);
      float inv = rsqrtf(s2*(1.0f/64.0f) - mu*mu + 1e-5f);
      sXA[m][w*16 + l15] = ftobf16(lng*(acc0[r]-mu)*inv + lnb);
    }
    {
      int m = 16+q*4+r;
      float4 pa = *(const float4*)&sLNp[m][0];
      float4 pb = *(const float4*)&sLNp[m][2];
      float s  = pa.x + pa.z + pb.x + pb.z;
      float s2 = pa.y + pa.w + pb.y + pb.w;
      float mu = s * (1.0f/64.0f);
      float inv = rsqrtf(s2*(1.0f/64.0f) - mu*mu + 1e-5f);
      sXA[m][w*16 + l15] = ftobf16(lng*(acc1[r]-mu)*inv + lnb);
    }
  }
  __syncthreads();   // #5

  // ---- MLP layer 1: [32x64]@[64x128], gelu ----
  f32x4 hacc[4];
  #pragma unroll
  for (int t=0;t<4;++t){ hacc[t][0]=0.f; hacc[t][1]=0.f; hacc[t][2]=0.f; hacc[t][3]=0.f; }
  {
    const unsigned short* ap = &sXA[mt*16 + l15][q*8];
    #pragma unroll
    for (int kk=0;kk<2;++kk){
      bf16x8 A = asbf(*(const uint4*)(ap + kk*32));
      #pragma unroll
      for (int t=0;t<4;++t)
        hacc[t] = __builtin_amdgcn_mfma_f32_16x16x32_bf16(A, asbf(b1B[t][kk]), hacc[t], 0,0,0);
    }
  }
  #pragma unroll
  for (int t=0;t<4;++t){
    int j = (ng*4+t)*16 + l15;
    float bb = sB1[j];
    #pragma unroll
    for (int r=0;r<4;++r){
      int m = mt*16 + q*4 + r;
      sH[m][j] = ftobf16(fast_gelu(hacc[t][r] + bb));
    }
  }
  __syncthreads();   // #6

  // ---- MLP layer 2: [32x128]@[128x64], +b2, store ----
  f32x4 oacc[2];
  #pragma unroll
  for (int t=0;t<2;++t){ oacc[t][0]=0.f; oacc[t][1]=0.f; oacc[t][2]=0.f; oacc[t][3]=0.f; }
  {
    const unsigned short* ap = &sH[mt*16 + l15][q*8];
    #pragma unroll
    for (int kk=0;kk<4;++kk){
      bf16x8 A = asbf(*(const uint4*)(ap + kk*32));
      #pragma unroll
      for (int t=0;t<2;++t)
        oacc[t] = __builtin_amdgcn_mfma_f32_16x16x32_bf16(A, asbf(b2B[t][kk]), oacc[t], 0,0,0);
    }
  }
  #pragma unroll
  for (int t=0;t<2;++t){
    int p = (ng*2+t)*16 + l15;
    float bb = sB2[p];
    #pragma unroll
    for (int r=0;r<4;++r){
      int m = mt*16 + q*4 + r;
      out[((size_t)n*KK + m)*64 + p] = oacc[t][r] + bb;
    }
  }
}

extern "C" void kernel_launch(void* const* d_in, const int* in_sizes, int n_in,
                              void* d_out, int out_size, void* d_ws, size_t ws_size,
                              hipStream_t stream) {
  (void)in_sizes; (void)n_in; (void)out_size; (void)ws_size;
  const float* pos    = (const float*)d_in[0];
  const float* dmap   = (const float*)d_in[1];
  const int*   nbr    = (const int*)  d_in[2];
  const int*   resi   = (const int*)  d_in[3];
  const int*   chain  = (const int*)  d_in[4];
  const int*   batch  = (const int*)  d_in[5];
  const float* mask   = (const float*)d_in[6];
  const float* W_rel  = (const float*)d_in[7];
  const float* W_dmap = (const float*)d_in[8];
  const float* W_dist = (const float*)d_in[9];
  const float* W_dir  = (const float*)d_in[10];
  const float* W_rot  = (const float*)d_in[11];
  const float* W_vec  = (const float*)d_in[12];
  const float* ln_g   = (const float*)d_in[13];
  const float* ln_b   = (const float*)d_in[14];
  const float* W1     = (const float*)d_in[15];
  const float* b1     = (const float*)d_in[16];
  const float* W2     = (const float*)d_in[17];
  const float* b2     = (const float*)d_in[18];
  float* out = (float*)d_out;

  unsigned short* wt  = (unsigned short*)d_ws;
  unsigned short* w1t = wt + 64*488;
  unsigned short* w2t = w1t + 128*64;

  prep_w<<<dim3(186), dim3(256), 0, stream>>>(W_dmap, W_dist, W_dir, W_rot, W_vec, W1, W2, wt);
  dsd_mfma<<<dim3(NN), dim3(256), 0, stream>>>(
      pos, dmap, nbr, resi, chain, batch, mask, W_rel,
      ln_g, ln_b, b1, b2, wt, w1t, w2t, out);
}